// Round 1
// baseline (194.714 us; speedup 1.0000x reference)
//
#include <hip/hip_runtime.h>

// Problem constants
#define E_SZ   512
#define NROWS  16384      // B*L
#define NR     100        // noise words
#define NW     112        // padded to 7 tiles of 16
#define MT     32         // rows per block
#define KC     64         // K-chunk
#define STR    72         // LDS row stride in bf16 elements (KC + 8 pad -> 144B rows)
#define NCHUNK (E_SZ / KC)

typedef __attribute__((ext_vector_type(8))) short short8;
typedef __attribute__((ext_vector_type(4))) float f32x4;

__device__ __forceinline__ unsigned short f2bf(float f) {
    unsigned int u = __float_as_uint(f);
    u += 0x7FFFu + ((u >> 16) & 1u);          // round-to-nearest-even
    return (unsigned short)(u >> 16);
}
__device__ __forceinline__ float bf2f(unsigned short h) {
    return __uint_as_float(((unsigned int)h) << 16);
}
__device__ __forceinline__ float softplus(float x) {
    return fmaxf(x, 0.f) + log1pf(__expf(-fabsf(x)));
}
__device__ __forceinline__ short8 cvt8(float4 a, float4 b) {
    short8 v;
    v[0] = (short)f2bf(a.x); v[1] = (short)f2bf(a.y);
    v[2] = (short)f2bf(a.z); v[3] = (short)f2bf(a.w);
    v[4] = (short)f2bf(b.x); v[5] = (short)f2bf(b.y);
    v[6] = (short)f2bf(b.z); v[7] = (short)f2bf(b.w);
    return v;
}

__global__ __launch_bounds__(256, 2)
void nce_loss_kernel(const float* __restrict__ inp,   // (N, E)
                     const float* __restrict__ emb,   // (V, E)
                     const float* __restrict__ bias,  // (V,)
                     const float* __restrict__ lpn,   // (V,) log p_noise
                     const int*   __restrict__ target,// (N,)
                     const int*   __restrict__ nidx,  // (NR,)
                     float* __restrict__ out)         // scalar
{
    // norm_term + log(noise_ratio), folded into per-word constants
    const float NTL = (float)(10.824907387009307 + 4.605170185988091);

    const int t  = threadIdx.x;
    const int r0 = blockIdx.x * MT;

    __shared__ __align__(16) unsigned short sIn[MT * STR];
    __shared__ __align__(16) unsigned short sNs[NW * STR];
    __shared__ float sBn[NW];    // bias - NT - lpn - LNR per noise word
    __shared__ float sTb[MT];    // same per target word
    __shared__ int   sTg[MT];
    __shared__ int   sNi[NW];
    __shared__ float sRed[MT * 8];
    __shared__ float sWs[4];

    if (t < NW) {
        int idx = (t < NR) ? nidx[t] : 0;
        sNi[t] = idx;
        sBn[t] = (t < NR) ? (bias[idx] - NTL - lpn[idx]) : 0.f;
    }
    if (t < MT) {
        int tg = target[r0 + t];
        sTg[t] = tg;
        sTb[t] = bias[tg] - NTL - lpn[tg];
    }
    __syncthreads();

    // staging / target-dot assignment: 8 threads per row, 8 k each
    const int rr = t >> 3;     // local row 0..31
    const int kg = t & 7;      // k-eighth 0..7
    float tacc = 0.f;

    // MFMA assignment: 4 waves; wave = (M-tile, N-half)
    const int w     = t >> 6;
    const int lane  = t & 63;
    const int c     = lane & 15;
    const int q     = lane >> 4;
    const int mrow  = (w >> 1) * 16 + c;    // A-fragment LDS row
    const int half  = w & 1;
    const int ntcnt = half ? 3 : 4;         // N-tiles: 0..3 or 4..6
    const int nbase = half * 4;

    f32x4 acc[4];
#pragma unroll
    for (int i = 0; i < 4; ++i) acc[i] = {0.f, 0.f, 0.f, 0.f};

    const float* inRow = inp + (size_t)(r0 + rr) * E_SZ + kg * 8;
    const float* tgRow = emb + (size_t)sTg[rr] * E_SZ + kg * 8;

    for (int kc = 0; kc < NCHUNK; ++kc) {
        const int k0 = kc * KC;

        // ---- stage input tile (f32 -> bf16), 1 b128 LDS write/thread ----
        {
            float4 x0 = *(const float4*)(inRow + k0);
            float4 x1 = *(const float4*)(inRow + k0 + 4);
            *(short8*)&sIn[rr * STR + kg * 8] = cvt8(x0, x1);
        }
        // ---- stage noise tile: 112 words x 8 k-groups = 896 tasks ----
        for (int task = t; task < NW * 8; task += 256) {
            int j = task >> 3, g = task & 7;
            short8 v = {0, 0, 0, 0, 0, 0, 0, 0};
            if (j < NR) {
                const float* p = emb + (size_t)sNi[j] * E_SZ + k0 + g * 8;
                float4 x0 = *(const float4*)p;
                float4 x1 = *(const float4*)(p + 4);
                v = cvt8(x0, x1);
            }
            *(short8*)&sNs[j * STR + g * 8] = v;
        }
        __syncthreads();

        // ---- target-score partial (fp32, gather of emb[target]) ----
        {
            float4 e0 = *(const float4*)(tgRow + k0);
            float4 e1 = *(const float4*)(tgRow + k0 + 4);
            short8 iv = *(const short8*)&sIn[rr * STR + kg * 8];
            tacc += bf2f((unsigned short)iv[0]) * e0.x
                  + bf2f((unsigned short)iv[1]) * e0.y
                  + bf2f((unsigned short)iv[2]) * e0.z
                  + bf2f((unsigned short)iv[3]) * e0.w
                  + bf2f((unsigned short)iv[4]) * e1.x
                  + bf2f((unsigned short)iv[5]) * e1.y
                  + bf2f((unsigned short)iv[6]) * e1.z
                  + bf2f((unsigned short)iv[7]) * e1.w;
        }

        // ---- MFMA: D[row][word] += A(in) * B(noise^T) ----
#pragma unroll
        for (int k32 = 0; k32 < 2; ++k32) {
            const int ko = k32 * 32 + q * 8;
            short8 A = *(const short8*)&sIn[mrow * STR + ko];
#pragma unroll
            for (int ti = 0; ti < 4; ++ti) {
                if (ti < ntcnt) {
                    short8 Bv = *(const short8*)&sNs[((nbase + ti) * 16 + c) * STR + ko];
                    acc[ti] = __builtin_amdgcn_mfma_f32_16x16x32_bf16(A, Bv, acc[ti], 0, 0, 0);
                }
            }
        }
        __syncthreads();
    }

    // ---- epilogue: noise terms ----
    float ll = 0.f;
#pragma unroll
    for (int ti = 0; ti < 4; ++ti) {
        if (ti < ntcnt) {
            int word = (nbase + ti) * 16 + c;
            if (word < NR) {
                float bn = sBn[word];
#pragma unroll
                for (int i = 0; i < 4; ++i) {
                    // C/D layout: col=lane&15 (word), row=q*4+i (unused here; all rows valid)
                    ll += softplus(acc[ti][i] + bn);
                }
            }
        }
    }

    // ---- target terms: reduce 8 partials per row ----
    sRed[t] = tacc;
    __syncthreads();
    if (t < MT) {
        float s = 0.f;
#pragma unroll
        for (int i = 0; i < 8; ++i) s += sRed[t * 8 + i];
        float xt = s + sTb[t];
        ll += softplus(-xt);   // softplus(x) - x == softplus(-x)
    }

    // ---- block reduction ----
#pragma unroll
    for (int off = 32; off > 0; off >>= 1) ll += __shfl_down(ll, off);
    if (lane == 0) sWs[w] = ll;
    __syncthreads();
    if (t == 0) {
        float s = (sWs[0] + sWs[1]) + (sWs[2] + sWs[3]);
        atomicAdd(out, s * (1.f / (float)NROWS));
    }
}

extern "C" void kernel_launch(void* const* d_in, const int* in_sizes, int n_in,
                              void* d_out, int out_size, void* d_ws, size_t ws_size,
                              hipStream_t stream) {
    const float* inp    = (const float*)d_in[0];
    const float* emb    = (const float*)d_in[1];
    const float* bias   = (const float*)d_in[2];
    const float* lpn    = (const float*)d_in[3];
    const int*   target = (const int*)d_in[4];
    const int*   nidx   = (const int*)d_in[5];
    float* out = (float*)d_out;

    hipMemsetAsync(out, 0, sizeof(float), stream);
    nce_loss_kernel<<<NROWS / MT, 256, 0, stream>>>(inp, emb, bias, lpn, target, nidx, out);
}